// Round 1
// baseline (2803.805 us; speedup 1.0000x reference)
//
#include <hip/hip_runtime.h>
#include <hip/hip_bf16.h>

// GCN: 2x GCNConv (symmetric norm, self-loops) + linear head.
// N=100000, E=3200000, IN=128, HID=64, LAB=121. All fp32.
//
// Self-loops are NOT materialized as edges: their contribution
// xw[i] * dinv[i]^2 is folded into the bias+ReLU epilogue, and deg gets +1
// inside the rsqrt kernel.

#define IN_DIM 128
#define HID 64
#define N_LAB 121

// ---- degree: atomicAdd ones over dst ----
__global__ void deg_kernel(const int* __restrict__ dst, float* __restrict__ deg, int E) {
    int e = blockIdx.x * blockDim.x + threadIdx.x;
    if (e < E) atomicAdd(&deg[dst[e]], 1.0f);
}

// ---- dinv = rsqrt(deg + 1)  (+1 = self loop) ----
__global__ void rsqrt_kernel(float* __restrict__ d, int N) {
    int i = blockIdx.x * blockDim.x + threadIdx.x;
    if (i < N) d[i] = rsqrtf(d[i] + 1.0f);
}

// ---- C[M,N] = A[M,K] @ B[K,N] (+bias). B staged in LDS. ----
// Block: 256 threads, 64 rows per block. Wave w handles row group w (rows
// row_base + w + 4*j), lanes = cols (col c0 and c0+64 when N>64).
template <int K, int N>
__global__ void gemm_kernel(const float* __restrict__ A, const float* __restrict__ B,
                            const float* __restrict__ bias, float* __restrict__ C, int M) {
    __shared__ float Bs[K * N];
    for (int i = threadIdx.x; i < K * N; i += 256) Bs[i] = B[i];
    __syncthreads();

    const int ROWS = 64;
    int row_base = blockIdx.x * ROWS;
    int c0 = threadIdx.x & 63;
    int ry = threadIdx.x >> 6;  // 0..3
    int rend = row_base + ROWS;
    if (rend > M) rend = M;

    for (int r = row_base + ry; r < rend; r += 4) {
        const float* Arow = A + (size_t)r * K;
        float acc0 = 0.f, acc1 = 0.f;
        #pragma unroll
        for (int k = 0; k < K; ++k) {
            float a = Arow[k];  // wave-uniform address -> broadcast
            acc0 += a * Bs[k * N + c0];
            if (N > 64) {
                if (c0 + 64 < N) acc1 += a * Bs[k * N + c0 + 64];
            }
        }
        float* Crow = C + (size_t)r * N;
        float bv0 = bias ? bias[c0] : 0.f;
        Crow[c0] = acc0 + bv0;
        if (N > 64) {
            if (c0 + 64 < N) {
                float bv1 = bias[c0 + 64];
                Crow[c0 + 64] = acc1 + bv1;
            }
        }
    }
}

// ---- scatter: one wave per edge, 64 lanes = 64 features ----
// agg[dst] += feat[src] * dinv[src] * dinv[dst]
__global__ void scatter_kernel(const float* __restrict__ feat,
                               const int* __restrict__ srcI, const int* __restrict__ dstI,
                               const float* __restrict__ dinv, float* __restrict__ agg,
                               int E) {
    size_t gid = (size_t)blockIdx.x * blockDim.x + threadIdx.x;
    int e = (int)(gid >> 6);
    int f = (int)(gid & 63);
    if (e >= E) return;
    int s = srcI[e];          // wave-uniform
    int d = dstI[e];          // wave-uniform
    float w = dinv[s] * dinv[d];
    float v = feat[(size_t)s * HID + f] * w;   // coalesced 256B row
    atomicAdd(&agg[(size_t)d * HID + f], v);   // coalesced, distinct addrs in-wave
}

// ---- epilogue: agg += self-loop term + bias, ReLU ----
__global__ void combine_relu(float* __restrict__ agg, const float* __restrict__ self_feat,
                             const float* __restrict__ dinv, const float* __restrict__ bias,
                             int N) {
    size_t gid = (size_t)blockIdx.x * blockDim.x + threadIdx.x;
    if (gid >= (size_t)N * HID) return;
    int i = (int)(gid >> 6);
    int f = (int)(gid & 63);
    float di = dinv[i];
    float v = agg[gid] + self_feat[gid] * di * di + bias[f];
    agg[gid] = fmaxf(v, 0.f);
}

extern "C" void kernel_launch(void* const* d_in, const int* in_sizes, int n_in,
                              void* d_out, int out_size, void* d_ws, size_t ws_size,
                              hipStream_t stream) {
    const float* x    = (const float*)d_in[0];
    const int*   ei   = (const int*)d_in[1];
    const float* W1   = (const float*)d_in[2];
    const float* b1   = (const float*)d_in[3];
    const float* W2   = (const float*)d_in[4];
    const float* b2   = (const float*)d_in[5];
    const float* Wout = (const float*)d_in[6];
    const float* bout = (const float*)d_in[7];
    float* out = (float*)d_out;

    const int N = in_sizes[0] / IN_DIM;   // 100000
    const int E = in_sizes[1] / 2;        // 3200000
    const int* srcI = ei;
    const int* dstI = ei + E;

    float* dinv = (float*)d_ws;
    float* bufA = dinv + N;               // [N, HID]
    float* bufB = bufA + (size_t)N * HID; // [N, HID]

    const size_t featBytes = (size_t)N * HID * sizeof(float);
    const int scatterBlocks = (int)(((size_t)E * HID + 255) / 256);
    const int elemBlocks = (int)(((size_t)N * HID + 255) / 256);

    // norm
    hipMemsetAsync(dinv, 0, (size_t)N * sizeof(float), stream);
    deg_kernel<<<(E + 255) / 256, 256, 0, stream>>>(dstI, dinv, E);
    rsqrt_kernel<<<(N + 255) / 256, 256, 0, stream>>>(dinv, N);

    // layer 1: bufA = x@W1; bufB = relu(scatter + self + b1)
    gemm_kernel<IN_DIM, HID><<<(N + 63) / 64, 256, 0, stream>>>(x, W1, nullptr, bufA, N);
    hipMemsetAsync(bufB, 0, featBytes, stream);
    scatter_kernel<<<scatterBlocks, 256, 0, stream>>>(bufA, srcI, dstI, dinv, bufB, E);
    combine_relu<<<elemBlocks, 256, 0, stream>>>(bufB, bufA, dinv, b1, N);

    // layer 2: bufA = h@W2; bufB = relu(scatter + self + b2)
    gemm_kernel<HID, HID><<<(N + 63) / 64, 256, 0, stream>>>(bufB, W2, nullptr, bufA, N);
    hipMemsetAsync(bufB, 0, featBytes, stream);
    scatter_kernel<<<scatterBlocks, 256, 0, stream>>>(bufA, srcI, dstI, dinv, bufB, E);
    combine_relu<<<elemBlocks, 256, 0, stream>>>(bufB, bufA, dinv, b2, N);

    // head: out = h2 @ Wout + bout
    gemm_kernel<HID, N_LAB><<<(N + 63) / 64, 256, 0, stream>>>(bufB, Wout, bout, out, N);
}

// Round 2
// 1803.439 us; speedup vs baseline: 1.5547x; 1.5547x over previous
//
#include <hip/hip_runtime.h>
#include <hip/hip_bf16.h>

// GCN: 2x GCNConv (symmetric norm, self-loops) + linear head.
// N=100000, E=3200000, IN=128, HID=64, LAB=121. All fp32.
//
// R2: GEMM rewritten — A tile staged to LDS via coalesced float4 loads.
// R1's wave-uniform scalar A-loads caused 33x HBM over-fetch (1.72 GB/dispatch,
// 850 us each). Self-loops folded into epilogue (deg+1, xw[i]*dinv[i]^2).

#define IN_DIM 128
#define HID 64
#define N_LAB 121

// ---- degree: atomicAdd ones over dst ----
__global__ void deg_kernel(const int* __restrict__ dst, float* __restrict__ deg, int E) {
    int e = blockIdx.x * blockDim.x + threadIdx.x;
    if (e < E) atomicAdd(&deg[dst[e]], 1.0f);
}

// ---- dinv = rsqrt(deg + 1)  (+1 = self loop) ----
__global__ void rsqrt_kernel(float* __restrict__ d, int N) {
    int i = blockIdx.x * blockDim.x + threadIdx.x;
    if (i < N) d[i] = rsqrtf(d[i] + 1.0f);
}

// ---- C[M,N] = A[M,K] @ B[K,N] (+bias). A tile + B staged in LDS. ----
// Block: 256 threads = 4 waves; 64 rows/block. Wave ry owns rows
// ry*16..ry*16+15 (local), lanes = cols c0 (and c0+64 when N>64).
// A-tile global loads are fully coalesced float4 (tile is one contiguous
// ROWS*K-float chunk). Compute reads: As broadcast (b128), Bs 2-way (free).
template <int K, int N>
__global__ void gemm_kernel(const float* __restrict__ A, const float* __restrict__ B,
                            const float* __restrict__ bias, float* __restrict__ C, int M) {
    constexpr int ROWS = 64;
    __shared__ float Bs[K * N];
    __shared__ float As[ROWS * K];

    for (int i = threadIdx.x; i < K * N; i += 256) Bs[i] = B[i];

    const int row_base = blockIdx.x * ROWS;
    const float* Ablk = A + (size_t)row_base * K;
    int avail = (M - row_base) * K;           // tail block may have < ROWS rows
    if (avail > ROWS * K) avail = ROWS * K;
    const int nvec = avail >> 2;              // K % 4 == 0
    const float4* __restrict__ Av = (const float4*)Ablk;
    float4* Asv = (float4*)As;
    for (int i = threadIdx.x; i < nvec; i += 256) Asv[i] = Av[i];
    __syncthreads();

    const int c0 = threadIdx.x & 63;
    const int ry = threadIdx.x >> 6;          // 0..3
    const bool col2 = (N > 64) && (c0 + 64 < N);

    float acc0[16], acc1[16];
    #pragma unroll
    for (int j = 0; j < 16; ++j) { acc0[j] = 0.f; acc1[j] = 0.f; }

    for (int k = 0; k < K; k += 4) {
        float b0[4], b1[4];
        #pragma unroll
        for (int kk = 0; kk < 4; ++kk) {
            b0[kk] = Bs[(k + kk) * N + c0];
            b1[kk] = col2 ? Bs[(k + kk) * N + c0 + 64] : 0.f;
        }
        #pragma unroll
        for (int j = 0; j < 16; ++j) {
            const float4 a = *(const float4*)&As[(ry * 16 + j) * K + k];  // broadcast
            acc0[j] = fmaf(a.x, b0[0], acc0[j]);
            acc0[j] = fmaf(a.y, b0[1], acc0[j]);
            acc0[j] = fmaf(a.z, b0[2], acc0[j]);
            acc0[j] = fmaf(a.w, b0[3], acc0[j]);
            if (N > 64) {
                acc1[j] = fmaf(a.x, b1[0], acc1[j]);
                acc1[j] = fmaf(a.y, b1[1], acc1[j]);
                acc1[j] = fmaf(a.z, b1[2], acc1[j]);
                acc1[j] = fmaf(a.w, b1[3], acc1[j]);
            }
        }
    }

    const float bv0 = bias ? bias[c0] : 0.f;
    const float bv1 = (bias && col2) ? bias[c0 + 64] : 0.f;
    #pragma unroll
    for (int j = 0; j < 16; ++j) {
        const int r = row_base + ry * 16 + j;
        if (r < M) {
            float* Crow = C + (size_t)r * N;
            Crow[c0] = acc0[j] + bv0;
            if (col2) Crow[c0 + 64] = acc1[j] + bv1;
        }
    }
}

// ---- scatter: one wave per edge, 64 lanes = 64 features ----
// agg[dst] += feat[src] * dinv[src] * dinv[dst]
__global__ void scatter_kernel(const float* __restrict__ feat,
                               const int* __restrict__ srcI, const int* __restrict__ dstI,
                               const float* __restrict__ dinv, float* __restrict__ agg,
                               int E) {
    size_t gid = (size_t)blockIdx.x * blockDim.x + threadIdx.x;
    int e = (int)(gid >> 6);
    int f = (int)(gid & 63);
    if (e >= E) return;
    int s = srcI[e];          // wave-uniform
    int d = dstI[e];          // wave-uniform
    float w = dinv[s] * dinv[d];
    float v = feat[(size_t)s * HID + f] * w;   // coalesced 256B row
    atomicAdd(&agg[(size_t)d * HID + f], v);   // coalesced, distinct addrs in-wave
}

// ---- epilogue: agg += self-loop term + bias, ReLU ----
__global__ void combine_relu(float* __restrict__ agg, const float* __restrict__ self_feat,
                             const float* __restrict__ dinv, const float* __restrict__ bias,
                             int N) {
    size_t gid = (size_t)blockIdx.x * blockDim.x + threadIdx.x;
    if (gid >= (size_t)N * HID) return;
    int i = (int)(gid >> 6);
    int f = (int)(gid & 63);
    float di = dinv[i];
    float v = agg[gid] + self_feat[gid] * di * di + bias[f];
    agg[gid] = fmaxf(v, 0.f);
}

extern "C" void kernel_launch(void* const* d_in, const int* in_sizes, int n_in,
                              void* d_out, int out_size, void* d_ws, size_t ws_size,
                              hipStream_t stream) {
    const float* x    = (const float*)d_in[0];
    const int*   ei   = (const int*)d_in[1];
    const float* W1   = (const float*)d_in[2];
    const float* b1   = (const float*)d_in[3];
    const float* W2   = (const float*)d_in[4];
    const float* b2   = (const float*)d_in[5];
    const float* Wout = (const float*)d_in[6];
    const float* bout = (const float*)d_in[7];
    float* out = (float*)d_out;

    const int N = in_sizes[0] / IN_DIM;   // 100000
    const int E = in_sizes[1] / 2;        // 3200000
    const int* srcI = ei;
    const int* dstI = ei + E;

    float* dinv = (float*)d_ws;
    float* bufA = dinv + N;               // [N, HID]
    float* bufB = bufA + (size_t)N * HID; // [N, HID]

    const size_t featBytes = (size_t)N * HID * sizeof(float);
    const int scatterBlocks = (int)(((size_t)E * HID + 255) / 256);
    const int elemBlocks = (int)(((size_t)N * HID + 255) / 256);
    const int gemmBlocks = (N + 63) / 64;

    // norm
    hipMemsetAsync(dinv, 0, (size_t)N * sizeof(float), stream);
    deg_kernel<<<(E + 255) / 256, 256, 0, stream>>>(dstI, dinv, E);
    rsqrt_kernel<<<(N + 255) / 256, 256, 0, stream>>>(dinv, N);

    // layer 1: bufA = x@W1; bufB = relu(scatter + self + b1)
    gemm_kernel<IN_DIM, HID><<<gemmBlocks, 256, 0, stream>>>(x, W1, nullptr, bufA, N);
    hipMemsetAsync(bufB, 0, featBytes, stream);
    scatter_kernel<<<scatterBlocks, 256, 0, stream>>>(bufA, srcI, dstI, dinv, bufB, E);
    combine_relu<<<elemBlocks, 256, 0, stream>>>(bufB, bufA, dinv, b1, N);

    // layer 2: bufA = h@W2; bufB = relu(scatter + self + b2)
    gemm_kernel<HID, HID><<<gemmBlocks, 256, 0, stream>>>(bufB, W2, nullptr, bufA, N);
    hipMemsetAsync(bufB, 0, featBytes, stream);
    scatter_kernel<<<scatterBlocks, 256, 0, stream>>>(bufA, srcI, dstI, dinv, bufB, E);
    combine_relu<<<elemBlocks, 256, 0, stream>>>(bufB, bufA, dinv, b2, N);

    // head: out = h2 @ Wout + bout
    gemm_kernel<HID, N_LAB><<<gemmBlocks, 256, 0, stream>>>(bufB, Wout, bout, out, N);
}

// Round 3
// 965.241 us; speedup vs baseline: 2.9048x; 1.8684x over previous
//
#include <hip/hip_runtime.h>
#include <hip/hip_bf16.h>

// GCN: 2x GCNConv (symmetric norm, self-loops) + linear head.
// N=100000, E=3200000, IN=128, HID=64, LAB=121. All fp32.
//
// R3: push-scatter (fp32 atomics, 800 MB write-through per layer) replaced by
// counting-sort CSR + pull-gather aggregation (register accumulate, one row
// write per node). dinv[src] folded into GEMM epilogue; self-loop + bias +
// ReLU fused into aggregate. deg comes from the sort histogram.

#define IN_DIM 128
#define HID 64
#define N_LAB 121

// ---- histogram over dst (int atomics, 400 KB L2-resident) ----
__global__ void hist_kernel(const int* __restrict__ dst, int* __restrict__ hist, int E) {
    int e = blockIdx.x * blockDim.x + threadIdx.x;
    if (e < E) atomicAdd(&hist[dst[e]], 1);
}

// ---- 3-kernel exclusive scan over N ints ----
__global__ void scan1(const int* __restrict__ in, int* __restrict__ out,
                      int* __restrict__ bsums, int n) {
    __shared__ int s[256];
    int i = blockIdx.x * 256 + threadIdx.x;
    int v = (i < n) ? in[i] : 0;
    s[threadIdx.x] = v;
    __syncthreads();
    for (int off = 1; off < 256; off <<= 1) {
        int t = (threadIdx.x >= off) ? s[threadIdx.x - off] : 0;
        __syncthreads();
        s[threadIdx.x] += t;
        __syncthreads();
    }
    if (i < n) out[i] = s[threadIdx.x] - v;  // exclusive
    if (threadIdx.x == 255) bsums[blockIdx.x] = s[255];
}

__global__ void scan2(int* __restrict__ bsums, int nb) {  // single block, nb <= 512
    __shared__ int s[512];
    int v = (threadIdx.x < nb) ? bsums[threadIdx.x] : 0;
    s[threadIdx.x] = v;
    __syncthreads();
    for (int off = 1; off < 512; off <<= 1) {
        int t = (threadIdx.x >= off) ? s[threadIdx.x - off] : 0;
        __syncthreads();
        s[threadIdx.x] += t;
        __syncthreads();
    }
    if (threadIdx.x < nb) bsums[threadIdx.x] = s[threadIdx.x] - v;  // exclusive
}

__global__ void scan3(int* __restrict__ row_ptr, const int* __restrict__ bsums,
                      int* __restrict__ cursor, int n, int E) {
    int i = blockIdx.x * 256 + threadIdx.x;
    if (i < n) {
        int v = row_ptr[i] + bsums[blockIdx.x];
        row_ptr[i] = v;
        cursor[i] = v;
    }
    if (i == 0) row_ptr[n] = E;
}

// ---- dinv = rsqrt(deg + 1), deg from CSR row extents ----
__global__ void rsqrt_kernel(const int* __restrict__ rp, float* __restrict__ dinv, int N) {
    int i = blockIdx.x * blockDim.x + threadIdx.x;
    if (i < N) dinv[i] = rsqrtf((float)(rp[i + 1] - rp[i]) + 1.0f);
}

// ---- counting-sort scatter: srcs grouped by dst ----
__global__ void sort_scatter(const int* __restrict__ src, const int* __restrict__ dst,
                             int* __restrict__ cursor, int* __restrict__ srcs, int E) {
    int e = blockIdx.x * blockDim.x + threadIdx.x;
    if (e < E) {
        int pos = atomicAdd(&cursor[dst[e]], 1);
        srcs[pos] = src[e];
    }
}

// ---- C[M,N] = (A[M,K] @ B[K,N]) * rowscale[r] + bias. LDS-staged. ----
template <int K, int N>
__global__ void gemm_kernel(const float* __restrict__ A, const float* __restrict__ B,
                            const float* __restrict__ bias, const float* __restrict__ rowscale,
                            float* __restrict__ C, int M) {
    constexpr int ROWS = 64;
    __shared__ float Bs[K * N];
    __shared__ float As[ROWS * K];

    for (int i = threadIdx.x; i < K * N; i += 256) Bs[i] = B[i];

    const int row_base = blockIdx.x * ROWS;
    const float* Ablk = A + (size_t)row_base * K;
    int avail = (M - row_base) * K;
    if (avail > ROWS * K) avail = ROWS * K;
    const int nvec = avail >> 2;  // K % 4 == 0
    const float4* __restrict__ Av = (const float4*)Ablk;
    float4* Asv = (float4*)As;
    for (int i = threadIdx.x; i < nvec; i += 256) Asv[i] = Av[i];
    __syncthreads();

    const int c0 = threadIdx.x & 63;
    const int ry = threadIdx.x >> 6;
    const bool col2 = (N > 64) && (c0 + 64 < N);

    float acc0[16], acc1[16];
    #pragma unroll
    for (int j = 0; j < 16; ++j) { acc0[j] = 0.f; acc1[j] = 0.f; }

    for (int k = 0; k < K; k += 4) {
        float b0[4], b1[4];
        #pragma unroll
        for (int kk = 0; kk < 4; ++kk) {
            b0[kk] = Bs[(k + kk) * N + c0];
            b1[kk] = col2 ? Bs[(k + kk) * N + c0 + 64] : 0.f;
        }
        #pragma unroll
        for (int j = 0; j < 16; ++j) {
            const float4 a = *(const float4*)&As[(ry * 16 + j) * K + k];
            acc0[j] = fmaf(a.x, b0[0], acc0[j]);
            acc0[j] = fmaf(a.y, b0[1], acc0[j]);
            acc0[j] = fmaf(a.z, b0[2], acc0[j]);
            acc0[j] = fmaf(a.w, b0[3], acc0[j]);
            if (N > 64) {
                acc1[j] = fmaf(a.x, b1[0], acc1[j]);
                acc1[j] = fmaf(a.y, b1[1], acc1[j]);
                acc1[j] = fmaf(a.z, b1[2], acc1[j]);
                acc1[j] = fmaf(a.w, b1[3], acc1[j]);
            }
        }
    }

    const float bv0 = bias ? bias[c0] : 0.f;
    const float bv1 = (bias && col2) ? bias[c0 + 64] : 0.f;
    #pragma unroll
    for (int j = 0; j < 16; ++j) {
        const int r = row_base + ry * 16 + j;
        if (r < M) {
            const float sc = rowscale ? rowscale[r] : 1.0f;
            float* Crow = C + (size_t)r * N;
            Crow[c0] = fmaf(acc0[j], sc, bv0);
            if (col2) Crow[c0 + 64] = fmaf(acc1[j], sc, bv1);
        }
    }
}

// ---- pull aggregation: one wave per dst node, lanes = 64 features ----
// out[r] = relu(dinv[r] * (feat2[r] + sum_{s in N_in(r)} feat2[s]) + bias)
// feat2 is already scaled by dinv[src] (GEMM epilogue).
__global__ __launch_bounds__(256) void aggregate(
        const float* __restrict__ feat2, const int* __restrict__ rp,
        const int* __restrict__ srcs, const float* __restrict__ dinv,
        const float* __restrict__ bias, float* __restrict__ out, int N) {
    size_t gid = (size_t)blockIdx.x * blockDim.x + threadIdx.x;
    int r = (int)(gid >> 6);
    int f = (int)(gid & 63);
    if (r >= N) return;
    int beg = rp[r], end = rp[r + 1];
    float acc = feat2[((size_t)r << 6) + f];  // self-loop term
    int e = beg;
    for (; e + 4 <= end; e += 4) {  // 4 independent gathers in flight
        int s0 = srcs[e], s1 = srcs[e + 1], s2 = srcs[e + 2], s3 = srcs[e + 3];
        float v0 = feat2[((size_t)s0 << 6) + f];
        float v1 = feat2[((size_t)s1 << 6) + f];
        float v2 = feat2[((size_t)s2 << 6) + f];
        float v3 = feat2[((size_t)s3 << 6) + f];
        acc += v0; acc += v1; acc += v2; acc += v3;
    }
    for (; e < end; ++e) acc += feat2[((size_t)srcs[e] << 6) + f];
    out[gid] = fmaxf(fmaf(acc, dinv[r], bias[f]), 0.f);
}

extern "C" void kernel_launch(void* const* d_in, const int* in_sizes, int n_in,
                              void* d_out, int out_size, void* d_ws, size_t ws_size,
                              hipStream_t stream) {
    const float* x    = (const float*)d_in[0];
    const int*   ei   = (const int*)d_in[1];
    const float* W1   = (const float*)d_in[2];
    const float* b1   = (const float*)d_in[3];
    const float* W2   = (const float*)d_in[4];
    const float* b2   = (const float*)d_in[5];
    const float* Wout = (const float*)d_in[6];
    const float* bout = (const float*)d_in[7];
    float* out = (float*)d_out;

    const int N = in_sizes[0] / IN_DIM;   // 100000
    const int E = in_sizes[1] / 2;        // 3200000
    const int* srcI = ei;
    const int* dstI = ei + E;

    // workspace carve-up
    int*   hist    = (int*)d_ws;                    // [N]
    int*   row_ptr = hist + N;                      // [N+1]
    int*   cursor  = row_ptr + (N + 1);             // [N]
    int*   bsums   = cursor + N;                    // [512]
    float* dinv    = (float*)(bsums + 512);         // [N]
    int*   srcs    = (int*)(dinv + N);              // [E]
    float* feat2   = (float*)(srcs + E);            // [N, HID]
    float* hbuf    = feat2 + (size_t)N * HID;       // [N, HID]

    const int nb = (N + 255) / 256;                 // scan blocks (391 <= 512)
    const int gemmBlocks = (N + 63) / 64;
    const int aggBlocks = (int)(((size_t)N * HID + 255) / 256);

    // ---- CSR build (once, reused by both layers) ----
    hipMemsetAsync(hist, 0, (size_t)N * sizeof(int), stream);
    hist_kernel<<<(E + 255) / 256, 256, 0, stream>>>(dstI, hist, E);
    scan1<<<nb, 256, 0, stream>>>(hist, row_ptr, bsums, N);
    scan2<<<1, 512, 0, stream>>>(bsums, nb);
    scan3<<<nb, 256, 0, stream>>>(row_ptr, bsums, cursor, N, E);
    rsqrt_kernel<<<(N + 255) / 256, 256, 0, stream>>>(row_ptr, dinv, N);
    sort_scatter<<<(E + 255) / 256, 256, 0, stream>>>(srcI, dstI, cursor, srcs, E);

    // ---- layer 1 ----
    gemm_kernel<IN_DIM, HID><<<gemmBlocks, 256, 0, stream>>>(x, W1, nullptr, dinv, feat2, N);
    aggregate<<<aggBlocks, 256, 0, stream>>>(feat2, row_ptr, srcs, dinv, b1, hbuf, N);

    // ---- layer 2 ----
    gemm_kernel<HID, HID><<<gemmBlocks, 256, 0, stream>>>(hbuf, W2, nullptr, dinv, feat2, N);
    aggregate<<<aggBlocks, 256, 0, stream>>>(feat2, row_ptr, srcs, dinv, b2, hbuf, N);

    // ---- head ----
    gemm_kernel<HID, N_LAB><<<gemmBlocks, 256, 0, stream>>>(hbuf, Wout, bout, nullptr, out, N);
}

// Round 4
// 825.080 us; speedup vs baseline: 3.3982x; 1.1699x over previous
//
#include <hip/hip_runtime.h>
#include <hip/hip_bf16.h>

// GCN: 2x GCNConv (symmetric norm, self-loops) + linear head.
// N=100000, E=3200000, IN=128, HID=64, LAB=121. All fp32.
//
// R4: single-pass counting sort (random 4B writes -> 195 MB line traffic,
// 280 us) replaced by two-level sort with block-private contiguous runs:
//   L1: 391 coarse buckets (dst>>8), per-block chunks, counts -> scan ->
//       scatter into private runs (packed (dstlow<<17)|src, full-line writes)
//   L2: one block per bucket, LDS hist256+scan, scatter into final CSR srcs
//       (bucket's CSR slice is contiguous + single-block-owned).
// bucketed[] aliases feat2 (dead until GEMM1). Aggregate = pull-gather with
// fused self-loop+bias+ReLU; dinv[src] folded into GEMM epilogue.

#define IN_DIM 128
#define HID 64
#define N_LAB 121
#define NB_BLK 256        // level-1 blocks (chunks)

// ---- histogram over dst (for row_ptr / degrees) ----
__global__ void hist_kernel(const int* __restrict__ dst, int* __restrict__ hist, int E) {
    int e = blockIdx.x * blockDim.x + threadIdx.x;
    if (e < E) atomicAdd(&hist[dst[e]], 1);
}

// ---- generic 3-kernel exclusive scan ----
__global__ void scan1(const int* __restrict__ in, int* __restrict__ out,
                      int* __restrict__ bsums, int n) {
    __shared__ int s[256];
    int i = blockIdx.x * 256 + threadIdx.x;
    int v = (i < n) ? in[i] : 0;
    s[threadIdx.x] = v;
    __syncthreads();
    for (int off = 1; off < 256; off <<= 1) {
        int t = (threadIdx.x >= off) ? s[threadIdx.x - off] : 0;
        __syncthreads();
        s[threadIdx.x] += t;
        __syncthreads();
    }
    if (i < n) out[i] = s[threadIdx.x] - v;  // exclusive
    if (threadIdx.x == 255) bsums[blockIdx.x] = s[255];
}

__global__ void scan2(int* __restrict__ bsums, int nb) {  // single block, nb <= 512
    __shared__ int s[512];
    int v = (threadIdx.x < nb) ? bsums[threadIdx.x] : 0;
    s[threadIdx.x] = v;
    __syncthreads();
    for (int off = 1; off < 512; off <<= 1) {
        int t = (threadIdx.x >= off) ? s[threadIdx.x - off] : 0;
        __syncthreads();
        s[threadIdx.x] += t;
        __syncthreads();
    }
    if (threadIdx.x < nb) bsums[threadIdx.x] = s[threadIdx.x] - v;  // exclusive
}

__global__ void scan_add(int* __restrict__ out, const int* __restrict__ bsums,
                         int n, int tailIdx, int tailVal) {
    int i = blockIdx.x * 256 + threadIdx.x;
    if (i < n) out[i] += bsums[blockIdx.x];
    if (tailIdx >= 0 && i == 0) out[tailIdx] = tailVal;
}

// ---- dinv = rsqrt(deg + 1), deg from CSR row extents ----
__global__ void rsqrt_kernel(const int* __restrict__ rp, float* __restrict__ dinv, int N) {
    int i = blockIdx.x * blockDim.x + threadIdx.x;
    if (i < N) dinv[i] = rsqrtf((float)(rp[i + 1] - rp[i]) + 1.0f);
}

// ---- L1 pass A: per-block per-bucket counts ----
__global__ __launch_bounds__(256) void bucket_count(const int* __restrict__ dst,
                                                    int* __restrict__ counts,
                                                    int nbuk, int chunk, int E) {
    extern __shared__ int c[];
    for (int j = threadIdx.x; j < nbuk; j += 256) c[j] = 0;
    __syncthreads();
    int beg = blockIdx.x * chunk;
    int end = min(beg + chunk, E);
    for (int i = beg + threadIdx.x; i < end; i += 256)
        atomicAdd(&c[dst[i] >> 8], 1);
    __syncthreads();
    for (int j = threadIdx.x; j < nbuk; j += 256)
        counts[j * NB_BLK + blockIdx.x] = c[j];
}

// ---- L1 pass B: scatter into private contiguous runs ----
__global__ __launch_bounds__(256) void bucket_scatter(const int* __restrict__ src,
                                                      const int* __restrict__ dst,
                                                      const int* __restrict__ base,
                                                      int* __restrict__ bucketed,
                                                      int nbuk, int chunk, int E) {
    extern __shared__ int c[];
    for (int j = threadIdx.x; j < nbuk; j += 256) c[j] = 0;
    __syncthreads();
    int beg = blockIdx.x * chunk;
    int end = min(beg + chunk, E);
    for (int i = beg + threadIdx.x; i < end; i += 256) {
        int d = dst[i];
        int b = d >> 8;
        int r = atomicAdd(&c[b], 1);
        int pos = base[b * NB_BLK + blockIdx.x] + r;
        bucketed[pos] = ((d & 255) << 17) | src[i];  // src < 2^17
    }
}

// ---- L2: within-bucket sort into final CSR srcs (one block per bucket) ----
__global__ __launch_bounds__(256) void bucket_sort(const int* __restrict__ bucketed,
                                                   const int* __restrict__ rp,
                                                   int* __restrict__ srcs, int N) {
    __shared__ int h[256];
    __shared__ int cur[256];
    int b = blockIdx.x;
    int nodeBase = b << 8;
    int nodeEnd = min(nodeBase + 256, N);
    int s = rp[nodeBase];
    int e = rp[nodeEnd];
    h[threadIdx.x] = 0;
    __syncthreads();
    for (int i = s + threadIdx.x; i < e; i += 256)
        atomicAdd(&h[bucketed[i] >> 17], 1);
    __syncthreads();
    int v = h[threadIdx.x];
    for (int off = 1; off < 256; off <<= 1) {  // inclusive Hillis-Steele
        int t = (threadIdx.x >= off) ? h[threadIdx.x - off] : 0;
        __syncthreads();
        h[threadIdx.x] += t;
        __syncthreads();
    }
    cur[threadIdx.x] = h[threadIdx.x] - v;     // exclusive offsets within bucket
    __syncthreads();
    for (int i = s + threadIdx.x; i < e; i += 256) {
        int p = bucketed[i];
        int d = p >> 17;
        int r = atomicAdd(&cur[d], 1);
        srcs[s + r] = p & 0x1FFFF;
    }
}

// ---- C[M,N] = (A[M,K] @ B[K,N]) * rowscale[r] + bias. LDS-staged. ----
template <int K, int N>
__global__ void gemm_kernel(const float* __restrict__ A, const float* __restrict__ B,
                            const float* __restrict__ bias, const float* __restrict__ rowscale,
                            float* __restrict__ C, int M) {
    constexpr int ROWS = 64;
    __shared__ float Bs[K * N];
    __shared__ float As[ROWS * K];

    for (int i = threadIdx.x; i < K * N; i += 256) Bs[i] = B[i];

    const int row_base = blockIdx.x * ROWS;
    const float* Ablk = A + (size_t)row_base * K;
    int avail = (M - row_base) * K;
    if (avail > ROWS * K) avail = ROWS * K;
    const int nvec = avail >> 2;  // K % 4 == 0
    const float4* __restrict__ Av = (const float4*)Ablk;
    float4* Asv = (float4*)As;
    for (int i = threadIdx.x; i < nvec; i += 256) Asv[i] = Av[i];
    __syncthreads();

    const int c0 = threadIdx.x & 63;
    const int ry = threadIdx.x >> 6;
    const bool col2 = (N > 64) && (c0 + 64 < N);

    float acc0[16], acc1[16];
    #pragma unroll
    for (int j = 0; j < 16; ++j) { acc0[j] = 0.f; acc1[j] = 0.f; }

    for (int k = 0; k < K; k += 4) {
        float b0[4], b1[4];
        #pragma unroll
        for (int kk = 0; kk < 4; ++kk) {
            b0[kk] = Bs[(k + kk) * N + c0];
            b1[kk] = col2 ? Bs[(k + kk) * N + c0 + 64] : 0.f;
        }
        #pragma unroll
        for (int j = 0; j < 16; ++j) {
            const float4 a = *(const float4*)&As[(ry * 16 + j) * K + k];
            acc0[j] = fmaf(a.x, b0[0], acc0[j]);
            acc0[j] = fmaf(a.y, b0[1], acc0[j]);
            acc0[j] = fmaf(a.z, b0[2], acc0[j]);
            acc0[j] = fmaf(a.w, b0[3], acc0[j]);
            if (N > 64) {
                acc1[j] = fmaf(a.x, b1[0], acc1[j]);
                acc1[j] = fmaf(a.y, b1[1], acc1[j]);
                acc1[j] = fmaf(a.z, b1[2], acc1[j]);
                acc1[j] = fmaf(a.w, b1[3], acc1[j]);
            }
        }
    }

    const float bv0 = bias ? bias[c0] : 0.f;
    const float bv1 = (bias && col2) ? bias[c0 + 64] : 0.f;
    #pragma unroll
    for (int j = 0; j < 16; ++j) {
        const int r = row_base + ry * 16 + j;
        if (r < M) {
            const float sc = rowscale ? rowscale[r] : 1.0f;
            float* Crow = C + (size_t)r * N;
            Crow[c0] = fmaf(acc0[j], sc, bv0);
            if (col2) Crow[c0 + 64] = fmaf(acc1[j], sc, bv1);
        }
    }
}

// ---- pull aggregation: one wave per dst node, lanes = 64 features ----
// out[r] = relu(dinv[r] * (feat2[r] + sum_{s in N_in(r)} feat2[s]) + bias)
__global__ __launch_bounds__(256) void aggregate(
        const float* __restrict__ feat2, const int* __restrict__ rp,
        const int* __restrict__ srcs, const float* __restrict__ dinv,
        const float* __restrict__ bias, float* __restrict__ out, int N) {
    size_t gid = (size_t)blockIdx.x * blockDim.x + threadIdx.x;
    int r = (int)(gid >> 6);
    int f = (int)(gid & 63);
    if (r >= N) return;
    int beg = rp[r], end = rp[r + 1];
    float acc = feat2[((size_t)r << 6) + f];  // self-loop term
    int e = beg;
    for (; e + 4 <= end; e += 4) {  // 4 independent gathers in flight
        int s0 = srcs[e], s1 = srcs[e + 1], s2 = srcs[e + 2], s3 = srcs[e + 3];
        float v0 = feat2[((size_t)s0 << 6) + f];
        float v1 = feat2[((size_t)s1 << 6) + f];
        float v2 = feat2[((size_t)s2 << 6) + f];
        float v3 = feat2[((size_t)s3 << 6) + f];
        acc += v0; acc += v1; acc += v2; acc += v3;
    }
    for (; e < end; ++e) acc += feat2[((size_t)srcs[e] << 6) + f];
    out[gid] = fmaxf(fmaf(acc, dinv[r], bias[f]), 0.f);
}

extern "C" void kernel_launch(void* const* d_in, const int* in_sizes, int n_in,
                              void* d_out, int out_size, void* d_ws, size_t ws_size,
                              hipStream_t stream) {
    const float* x    = (const float*)d_in[0];
    const int*   ei   = (const int*)d_in[1];
    const float* W1   = (const float*)d_in[2];
    const float* b1   = (const float*)d_in[3];
    const float* W2   = (const float*)d_in[4];
    const float* b2   = (const float*)d_in[5];
    const float* Wout = (const float*)d_in[6];
    const float* bout = (const float*)d_in[7];
    float* out = (float*)d_out;

    const int N = in_sizes[0] / IN_DIM;   // 100000
    const int E = in_sizes[1] / 2;        // 3200000
    const int* srcI = ei;
    const int* dstI = ei + E;

    const int nbuk = (N + 255) >> 8;      // 391 coarse buckets
    const int M1 = nbuk * NB_BLK;         // 100096 count entries
    const int chunk = (E + NB_BLK - 1) / NB_BLK;

    // workspace carve-up
    int*   hist    = (int*)d_ws;                    // [N]
    int*   row_ptr = hist + N;                      // [N+1]
    int*   bsums   = row_ptr + (N + 1);             // [512]
    float* dinv    = (float*)(bsums + 512);         // [N]
    int*   counts  = (int*)(dinv + N);              // [M1]
    int*   base    = counts + M1;                   // [M1]
    int*   bsums2  = base + M1;                     // [512]
    int*   srcs    = bsums2 + 512;                  // [E]
    float* feat2   = (float*)(srcs + E);            // [N, HID]
    float* hbuf    = feat2 + (size_t)N * HID;       // [N, HID]
    int*   bucketed = (int*)feat2;                  // [E] aliases feat2 (dead until GEMM1)

    const int nbN = (N + 255) / 256;                // 391
    const int nbM = (M1 + 255) / 256;               // 391
    const int gemmBlocks = (N + 63) / 64;
    const int aggBlocks = (int)(((size_t)N * HID + 255) / 256);
    const size_t ldsBuk = (size_t)nbuk * sizeof(int);

    // ---- CSR row_ptr + dinv ----
    hipMemsetAsync(hist, 0, (size_t)N * sizeof(int), stream);
    hist_kernel<<<(E + 255) / 256, 256, 0, stream>>>(dstI, hist, E);
    scan1<<<nbN, 256, 0, stream>>>(hist, row_ptr, bsums, N);
    scan2<<<1, 512, 0, stream>>>(bsums, nbN);
    scan_add<<<nbN, 256, 0, stream>>>(row_ptr, bsums, N, N, E);
    rsqrt_kernel<<<(N + 255) / 256, 256, 0, stream>>>(row_ptr, dinv, N);

    // ---- two-level sort: edges grouped by dst into srcs ----
    bucket_count<<<NB_BLK, 256, ldsBuk, stream>>>(dstI, counts, nbuk, chunk, E);
    scan1<<<nbM, 256, 0, stream>>>(counts, base, bsums2, M1);
    scan2<<<1, 512, 0, stream>>>(bsums2, nbM);
    scan_add<<<nbM, 256, 0, stream>>>(base, bsums2, M1, -1, 0);
    bucket_scatter<<<NB_BLK, 256, ldsBuk, stream>>>(srcI, dstI, base, bucketed, nbuk, chunk, E);
    bucket_sort<<<nbuk, 256, 0, stream>>>(bucketed, row_ptr, srcs, N);

    // ---- layer 1 ----
    gemm_kernel<IN_DIM, HID><<<gemmBlocks, 256, 0, stream>>>(x, W1, nullptr, dinv, feat2, N);
    aggregate<<<aggBlocks, 256, 0, stream>>>(feat2, row_ptr, srcs, dinv, b1, hbuf, N);

    // ---- layer 2 ----
    gemm_kernel<HID, HID><<<gemmBlocks, 256, 0, stream>>>(hbuf, W2, nullptr, dinv, feat2, N);
    aggregate<<<aggBlocks, 256, 0, stream>>>(feat2, row_ptr, srcs, dinv, b2, hbuf, N);

    // ---- head ----
    gemm_kernel<HID, N_LAB><<<gemmBlocks, 256, 0, stream>>>(hbuf, Wout, bout, nullptr, out, N);
}

// Round 5
// 604.380 us; speedup vs baseline: 4.6391x; 1.3652x over previous
//
#include <hip/hip_runtime.h>
#include <hip/hip_bf16.h>
#include <hip/hip_fp16.h>

// GCN: 2x GCNConv (symmetric norm, self-loops) + linear head.
// N=100000, E=3200000, IN=128, HID=64, LAB=121.
//
// R5: (a) feat2 (the gather target of aggregate) stored fp16 -> 128B rows,
// halves gather payload AND working set (25.6->12.8 MB, better L2 hit rate).
// fp32 accumulation; added logit error ~5e-4 << 4.5e-3 threshold.
// (b) per-node histogram pipeline deleted: bucket scan base[b*256] IS
// row_ptr[b<<8]; bucket_sort's LDS hist emits row_ptr + dinv directly.
// Two-level dst-sort (R4) retained: private contiguous runs -> full-line writes.

#define IN_DIM 128
#define HID 64
#define N_LAB 121
#define NB_BLK 256        // level-1 blocks (chunks)

// ---- generic 3-kernel exclusive scan (used for the M1 = nbuk*NB_BLK counts) ----
__global__ void scan1(const int* __restrict__ in, int* __restrict__ out,
                      int* __restrict__ bsums, int n) {
    __shared__ int s[256];
    int i = blockIdx.x * 256 + threadIdx.x;
    int v = (i < n) ? in[i] : 0;
    s[threadIdx.x] = v;
    __syncthreads();
    for (int off = 1; off < 256; off <<= 1) {
        int t = (threadIdx.x >= off) ? s[threadIdx.x - off] : 0;
        __syncthreads();
        s[threadIdx.x] += t;
        __syncthreads();
    }
    if (i < n) out[i] = s[threadIdx.x] - v;  // exclusive
    if (threadIdx.x == 255) bsums[blockIdx.x] = s[255];
}

__global__ void scan2(int* __restrict__ bsums, int nb) {  // single block, nb <= 512
    __shared__ int s[512];
    int v = (threadIdx.x < nb) ? bsums[threadIdx.x] : 0;
    s[threadIdx.x] = v;
    __syncthreads();
    for (int off = 1; off < 512; off <<= 1) {
        int t = (threadIdx.x >= off) ? s[threadIdx.x - off] : 0;
        __syncthreads();
        s[threadIdx.x] += t;
        __syncthreads();
    }
    if (threadIdx.x < nb) bsums[threadIdx.x] = s[threadIdx.x] - v;  // exclusive
}

__global__ void scan_add(int* __restrict__ out, const int* __restrict__ bsums, int n) {
    int i = blockIdx.x * 256 + threadIdx.x;
    if (i < n) out[i] += bsums[blockIdx.x];
}

// ---- L1 pass A: per-block per-bucket counts ----
__global__ __launch_bounds__(256) void bucket_count(const int* __restrict__ dst,
                                                    int* __restrict__ counts,
                                                    int nbuk, int chunk, int E) {
    extern __shared__ int c[];
    for (int j = threadIdx.x; j < nbuk; j += 256) c[j] = 0;
    __syncthreads();
    int beg = blockIdx.x * chunk;
    int end = min(beg + chunk, E);
    for (int i = beg + threadIdx.x; i < end; i += 256)
        atomicAdd(&c[dst[i] >> 8], 1);
    __syncthreads();
    for (int j = threadIdx.x; j < nbuk; j += 256)
        counts[j * NB_BLK + blockIdx.x] = c[j];
}

// ---- L1 pass B: scatter into private contiguous runs ----
__global__ __launch_bounds__(256) void bucket_scatter(const int* __restrict__ src,
                                                      const int* __restrict__ dst,
                                                      const int* __restrict__ base,
                                                      int* __restrict__ bucketed,
                                                      int nbuk, int chunk, int E) {
    extern __shared__ int c[];
    for (int j = threadIdx.x; j < nbuk; j += 256) c[j] = 0;
    __syncthreads();
    int beg = blockIdx.x * chunk;
    int end = min(beg + chunk, E);
    for (int i = beg + threadIdx.x; i < end; i += 256) {
        int d = dst[i];
        int b = d >> 8;
        int r = atomicAdd(&c[b], 1);
        int pos = base[b * NB_BLK + blockIdx.x] + r;
        bucketed[pos] = ((d & 255) << 17) | src[i];  // src < 2^17
    }
}

// ---- L2: within-bucket sort into final CSR srcs; emits row_ptr + dinv ----
// Bucket b's slice start = base[b*NB_BLK] (scan over bucket-major counts).
__global__ __launch_bounds__(256) void bucket_sort(const int* __restrict__ bucketed,
                                                   const int* __restrict__ base,
                                                   int* __restrict__ srcs,
                                                   int* __restrict__ row_ptr,
                                                   float* __restrict__ dinv,
                                                   int nbuk, int N, int E) {
    __shared__ int h[256];
    __shared__ int cur[256];
    int b = blockIdx.x;
    int nodeBase = b << 8;
    int s = base[b * NB_BLK];
    int e = (b == nbuk - 1) ? E : base[(b + 1) * NB_BLK];
    h[threadIdx.x] = 0;
    __syncthreads();
    for (int i = s + threadIdx.x; i < e; i += 256)
        atomicAdd(&h[bucketed[i] >> 17], 1);
    __syncthreads();
    int v = h[threadIdx.x];
    for (int off = 1; off < 256; off <<= 1) {  // inclusive Hillis-Steele
        int t = (threadIdx.x >= off) ? h[threadIdx.x - off] : 0;
        __syncthreads();
        h[threadIdx.x] += t;
        __syncthreads();
    }
    int excl = h[threadIdx.x] - v;
    cur[threadIdx.x] = excl;
    int node = nodeBase + threadIdx.x;
    if (node < N) {
        row_ptr[node] = s + excl;
        dinv[node] = rsqrtf((float)v + 1.0f);  // +1 = self loop
    }
    if (b == nbuk - 1 && threadIdx.x == 0) row_ptr[N] = E;
    __syncthreads();
    for (int i = s + threadIdx.x; i < e; i += 256) {
        int p = bucketed[i];
        int d = p >> 17;
        int r = atomicAdd(&cur[d], 1);
        srcs[s + r] = p & 0x1FFFF;
    }
}

// ---- C[M,N] = (A[M,K] @ B[K,N]) * rowscale[r] + bias. LDS-staged. ----
template <int K, int N, typename OT>
__global__ void gemm_kernel(const float* __restrict__ A, const float* __restrict__ B,
                            const float* __restrict__ bias, const float* __restrict__ rowscale,
                            OT* __restrict__ C, int M) {
    constexpr int ROWS = 64;
    __shared__ float Bs[K * N];
    __shared__ float As[ROWS * K];

    for (int i = threadIdx.x; i < K * N; i += 256) Bs[i] = B[i];

    const int row_base = blockIdx.x * ROWS;
    const float* Ablk = A + (size_t)row_base * K;
    int avail = (M - row_base) * K;
    if (avail > ROWS * K) avail = ROWS * K;
    const int nvec = avail >> 2;  // K % 4 == 0
    const float4* __restrict__ Av = (const float4*)Ablk;
    float4* Asv = (float4*)As;
    for (int i = threadIdx.x; i < nvec; i += 256) Asv[i] = Av[i];
    __syncthreads();

    const int c0 = threadIdx.x & 63;
    const int ry = threadIdx.x >> 6;
    const bool col2 = (N > 64) && (c0 + 64 < N);

    float acc0[16], acc1[16];
    #pragma unroll
    for (int j = 0; j < 16; ++j) { acc0[j] = 0.f; acc1[j] = 0.f; }

    for (int k = 0; k < K; k += 4) {
        float b0[4], b1[4];
        #pragma unroll
        for (int kk = 0; kk < 4; ++kk) {
            b0[kk] = Bs[(k + kk) * N + c0];
            b1[kk] = col2 ? Bs[(k + kk) * N + c0 + 64] : 0.f;
        }
        #pragma unroll
        for (int j = 0; j < 16; ++j) {
            const float4 a = *(const float4*)&As[(ry * 16 + j) * K + k];
            acc0[j] = fmaf(a.x, b0[0], acc0[j]);
            acc0[j] = fmaf(a.y, b0[1], acc0[j]);
            acc0[j] = fmaf(a.z, b0[2], acc0[j]);
            acc0[j] = fmaf(a.w, b0[3], acc0[j]);
            if (N > 64) {
                acc1[j] = fmaf(a.x, b1[0], acc1[j]);
                acc1[j] = fmaf(a.y, b1[1], acc1[j]);
                acc1[j] = fmaf(a.z, b1[2], acc1[j]);
                acc1[j] = fmaf(a.w, b1[3], acc1[j]);
            }
        }
    }

    const float bv0 = bias ? bias[c0] : 0.f;
    const float bv1 = (bias && col2) ? bias[c0 + 64] : 0.f;
    #pragma unroll
    for (int j = 0; j < 16; ++j) {
        const int r = row_base + ry * 16 + j;
        if (r < M) {
            const float sc = rowscale ? rowscale[r] : 1.0f;
            OT* Crow = C + (size_t)r * N;
            Crow[c0] = (OT)fmaf(acc0[j], sc, bv0);
            if (col2) Crow[c0 + 64] = (OT)fmaf(acc1[j], sc, bv1);
        }
    }
}

// ---- pull aggregation: one wave per dst node, lanes = 64 features ----
// out[r] = relu(dinv[r] * (feat2[r] + sum_{s in N_in(r)} feat2[s]) + bias)
// feat2 is fp16 (128 B/row gather), already scaled by dinv[src]; fp32 accum.
__global__ __launch_bounds__(256) void aggregate(
        const __half* __restrict__ feat2, const int* __restrict__ rp,
        const int* __restrict__ srcs, const float* __restrict__ dinv,
        const float* __restrict__ bias, float* __restrict__ out, int N) {
    size_t gid = (size_t)blockIdx.x * blockDim.x + threadIdx.x;
    int r = (int)(gid >> 6);
    int f = (int)(gid & 63);
    if (r >= N) return;
    int beg = rp[r], end = rp[r + 1];
    float acc = __half2float(feat2[((size_t)r << 6) + f]);  // self-loop term
    int e = beg;
    for (; e + 4 <= end; e += 4) {  // 4 independent gathers in flight
        int s0 = srcs[e], s1 = srcs[e + 1], s2 = srcs[e + 2], s3 = srcs[e + 3];
        float v0 = __half2float(feat2[((size_t)s0 << 6) + f]);
        float v1 = __half2float(feat2[((size_t)s1 << 6) + f]);
        float v2 = __half2float(feat2[((size_t)s2 << 6) + f]);
        float v3 = __half2float(feat2[((size_t)s3 << 6) + f]);
        acc += v0; acc += v1; acc += v2; acc += v3;
    }
    for (; e < end; ++e) acc += __half2float(feat2[((size_t)srcs[e] << 6) + f]);
    out[gid] = fmaxf(fmaf(acc, dinv[r], bias[f]), 0.f);
}

extern "C" void kernel_launch(void* const* d_in, const int* in_sizes, int n_in,
                              void* d_out, int out_size, void* d_ws, size_t ws_size,
                              hipStream_t stream) {
    const float* x    = (const float*)d_in[0];
    const int*   ei   = (const int*)d_in[1];
    const float* W1   = (const float*)d_in[2];
    const float* b1   = (const float*)d_in[3];
    const float* W2   = (const float*)d_in[4];
    const float* b2   = (const float*)d_in[5];
    const float* Wout = (const float*)d_in[6];
    const float* bout = (const float*)d_in[7];
    float* out = (float*)d_out;

    const int N = in_sizes[0] / IN_DIM;   // 100000
    const int E = in_sizes[1] / 2;        // 3200000
    const int* srcI = ei;
    const int* dstI = ei + E;

    const int nbuk = (N + 255) >> 8;      // 391 coarse buckets
    const int M1 = nbuk * NB_BLK;         // 100096 count entries
    const int chunk = (E + NB_BLK - 1) / NB_BLK;

    // workspace carve-up
    int*    row_ptr = (int*)d_ws;                   // [N+1]
    float*  dinv    = (float*)(row_ptr + (N + 1));  // [N]
    int*    counts  = (int*)(dinv + N);             // [M1]
    int*    base    = counts + M1;                  // [M1]
    int*    bsums2  = base + M1;                    // [512]
    int*    srcs    = bsums2 + 512;                 // [E]
    __half* feat2   = (__half*)(srcs + E);          // [N, HID] fp16 (12.8 MB)
    float*  hbuf    = (float*)(feat2 + (size_t)N * HID);  // [N, HID] fp32
    int*    bucketed = (int*)feat2;                 // [E] ints = 12.8 MB, aliases feat2

    const int nbM = (M1 + 255) / 256;               // 391
    const int gemmBlocks = (N + 63) / 64;
    const int aggBlocks = (int)(((size_t)N * HID + 255) / 256);
    const size_t ldsBuk = (size_t)nbuk * sizeof(int);

    // ---- two-level sort: edges grouped by dst into srcs; emits row_ptr+dinv ----
    bucket_count<<<NB_BLK, 256, ldsBuk, stream>>>(dstI, counts, nbuk, chunk, E);
    scan1<<<nbM, 256, 0, stream>>>(counts, base, bsums2, M1);
    scan2<<<1, 512, 0, stream>>>(bsums2, nbM);
    scan_add<<<nbM, 256, 0, stream>>>(base, bsums2, M1);
    bucket_scatter<<<NB_BLK, 256, ldsBuk, stream>>>(srcI, dstI, base, bucketed, nbuk, chunk, E);
    bucket_sort<<<nbuk, 256, 0, stream>>>(bucketed, base, srcs, row_ptr, dinv, nbuk, N, E);

    // ---- layer 1 ----
    gemm_kernel<IN_DIM, HID, __half><<<gemmBlocks, 256, 0, stream>>>(x, W1, nullptr, dinv, feat2, N);
    aggregate<<<aggBlocks, 256, 0, stream>>>(feat2, row_ptr, srcs, dinv, b1, hbuf, N);

    // ---- layer 2 ----
    gemm_kernel<HID, HID, __half><<<gemmBlocks, 256, 0, stream>>>(hbuf, W2, nullptr, dinv, feat2, N);
    aggregate<<<aggBlocks, 256, 0, stream>>>(feat2, row_ptr, srcs, dinv, b2, hbuf, N);

    // ---- head ----
    gemm_kernel<HID, N_LAB, float><<<gemmBlocks, 256, 0, stream>>>(hbuf, Wout, bout, nullptr, out, N);
}

// Round 6
// 552.061 us; speedup vs baseline: 5.0788x; 1.0948x over previous
//
#include <hip/hip_runtime.h>
#include <hip/hip_bf16.h>
#include <hip/hip_fp16.h>

// GCN: 2x GCNConv (symmetric norm, self-loops) + linear head.
// N=100000, E=3200000, IN=128, HID=64, LAB=121.
//
// R6: GEMM inner loop re-tiled. R5's per-column mapping issued ~640 LDS
// instrs/thread (scalar Bs reads) -> LDS-issue-bound (~150 us across the 3
// GEMMs vs a ~10 us VALU floor for GEMM1). New mapping: 4 rows x 4 cols per
// thread, k-quads; 8 b128 LDS reads per 64 fmaf, A-reads are wave-broadcast.
// Packed float4/__half2 epilogue stores. Aggregate unroll 4->8.
// Retained from R4/R5: two-level dst sort with block-private full-line runs;
// fp16 feat2 (halves gather payload + working set); bucket_sort emits
// row_ptr+dinv (no per-node histogram pass); self-loop folded as deg+1 and
// epilogue term; dinv[src] folded into GEMM rowscale.

#define IN_DIM 128
#define HID 64
#define N_LAB 121
#define NB_BLK 256        // level-1 blocks (chunks)

// ---- generic 3-kernel exclusive scan (used for the M1 = nbuk*NB_BLK counts) ----
__global__ void scan1(const int* __restrict__ in, int* __restrict__ out,
                      int* __restrict__ bsums, int n) {
    __shared__ int s[256];
    int i = blockIdx.x * 256 + threadIdx.x;
    int v = (i < n) ? in[i] : 0;
    s[threadIdx.x] = v;
    __syncthreads();
    for (int off = 1; off < 256; off <<= 1) {
        int t = (threadIdx.x >= off) ? s[threadIdx.x - off] : 0;
        __syncthreads();
        s[threadIdx.x] += t;
        __syncthreads();
    }
    if (i < n) out[i] = s[threadIdx.x] - v;  // exclusive
    if (threadIdx.x == 255) bsums[blockIdx.x] = s[255];
}

__global__ void scan2(int* __restrict__ bsums, int nb) {  // single block, nb <= 512
    __shared__ int s[512];
    int v = (threadIdx.x < nb) ? bsums[threadIdx.x] : 0;
    s[threadIdx.x] = v;
    __syncthreads();
    for (int off = 1; off < 512; off <<= 1) {
        int t = (threadIdx.x >= off) ? s[threadIdx.x - off] : 0;
        __syncthreads();
        s[threadIdx.x] += t;
        __syncthreads();
    }
    if (threadIdx.x < nb) bsums[threadIdx.x] = s[threadIdx.x] - v;  // exclusive
}

__global__ void scan_add(int* __restrict__ out, const int* __restrict__ bsums, int n) {
    int i = blockIdx.x * 256 + threadIdx.x;
    if (i < n) out[i] += bsums[blockIdx.x];
}

// ---- L1 pass A: per-block per-bucket counts ----
__global__ __launch_bounds__(256) void bucket_count(const int* __restrict__ dst,
                                                    int* __restrict__ counts,
                                                    int nbuk, int chunk, int E) {
    extern __shared__ int c[];
    for (int j = threadIdx.x; j < nbuk; j += 256) c[j] = 0;
    __syncthreads();
    int beg = blockIdx.x * chunk;
    int end = min(beg + chunk, E);
    for (int i = beg + threadIdx.x; i < end; i += 256)
        atomicAdd(&c[dst[i] >> 8], 1);
    __syncthreads();
    for (int j = threadIdx.x; j < nbuk; j += 256)
        counts[j * NB_BLK + blockIdx.x] = c[j];
}

// ---- L1 pass B: scatter into private contiguous runs ----
__global__ __launch_bounds__(256) void bucket_scatter(const int* __restrict__ src,
                                                      const int* __restrict__ dst,
                                                      const int* __restrict__ base,
                                                      int* __restrict__ bucketed,
                                                      int nbuk, int chunk, int E) {
    extern __shared__ int c[];
    for (int j = threadIdx.x; j < nbuk; j += 256) c[j] = 0;
    __syncthreads();
    int beg = blockIdx.x * chunk;
    int end = min(beg + chunk, E);
    for (int i = beg + threadIdx.x; i < end; i += 256) {
        int d = dst[i];
        int b = d >> 8;
        int r = atomicAdd(&c[b], 1);
        int pos = base[b * NB_BLK + blockIdx.x] + r;
        bucketed[pos] = ((d & 255) << 17) | src[i];  // src < 2^17
    }
}

// ---- L2: within-bucket sort into final CSR srcs; emits row_ptr + dinv ----
__global__ __launch_bounds__(256) void bucket_sort(const int* __restrict__ bucketed,
                                                   const int* __restrict__ base,
                                                   int* __restrict__ srcs,
                                                   int* __restrict__ row_ptr,
                                                   float* __restrict__ dinv,
                                                   int nbuk, int N, int E) {
    __shared__ int h[256];
    __shared__ int cur[256];
    int b = blockIdx.x;
    int nodeBase = b << 8;
    int s = base[b * NB_BLK];
    int e = (b == nbuk - 1) ? E : base[(b + 1) * NB_BLK];
    h[threadIdx.x] = 0;
    __syncthreads();
    for (int i = s + threadIdx.x; i < e; i += 256)
        atomicAdd(&h[bucketed[i] >> 17], 1);
    __syncthreads();
    int v = h[threadIdx.x];
    for (int off = 1; off < 256; off <<= 1) {  // inclusive Hillis-Steele
        int t = (threadIdx.x >= off) ? h[threadIdx.x - off] : 0;
        __syncthreads();
        h[threadIdx.x] += t;
        __syncthreads();
    }
    int excl = h[threadIdx.x] - v;
    cur[threadIdx.x] = excl;
    int node = nodeBase + threadIdx.x;
    if (node < N) {
        row_ptr[node] = s + excl;
        dinv[node] = rsqrtf((float)v + 1.0f);  // +1 = self loop
    }
    if (b == nbuk - 1 && threadIdx.x == 0) row_ptr[N] = E;
    __syncthreads();
    for (int i = s + threadIdx.x; i < e; i += 256) {
        int p = bucketed[i];
        int d = p >> 17;
        int r = atomicAdd(&cur[d], 1);
        srcs[s + r] = p & 0x1FFFF;
    }
}

// ---- C[M,N] = (A[M,K] @ B[K,N]) * rowscale[r] + bias. LDS-staged, 2D reg tile ----
// 64-row tile. Thread (cg, rg) owns cols 4cg..4cg+3 and rows rg + RG*j.
// Per k-quad: 4 b128 A reads (broadcast across cg) + 4 b128 B reads -> 64 fmaf.
template <int K, int N, typename OT>
__global__ __launch_bounds__(256) void gemm_kernel(
        const float* __restrict__ A, const float* __restrict__ B,
        const float* __restrict__ bias, const float* __restrict__ rowscale,
        OT* __restrict__ C, int M) {
    constexpr int ROWS = 64;
    constexpr int NPAD = (N <= 64) ? 64 : 128;
    constexpr int CG = NPAD / 4;     // column groups (16 or 32)
    constexpr int RG = 256 / CG;     // thread rows (16 or 8)
    constexpr int RPT = ROWS / RG;   // rows per thread (4 or 8)
    __shared__ float Bs[K * NPAD];
    __shared__ float As[ROWS * K];

    // stage B (zero-pad cols N..NPAD)
    for (int i = threadIdx.x; i < K * NPAD; i += 256) {
        int c = i & (NPAD - 1);
        int k = i / NPAD;
        Bs[i] = (c < N) ? B[k * N + c] : 0.f;
    }
    // stage A tile (coalesced float4); tail block loads only valid rows
    const int row_base = blockIdx.x * ROWS;
    const float* Ablk = A + (size_t)row_base * K;
    int avail = (M - row_base) * K;
    if (avail > ROWS * K) avail = ROWS * K;
    const int nvec = avail >> 2;  // K % 4 == 0
    const float4* __restrict__ Av = (const float4*)Ablk;
    float4* Asv = (float4*)As;
    for (int i = threadIdx.x; i < nvec; i += 256) Asv[i] = Av[i];
    __syncthreads();

    const int cg = threadIdx.x % CG;
    const int rg = threadIdx.x / CG;

    float acc[RPT][4];
    #pragma unroll
    for (int j = 0; j < RPT; ++j) {
        acc[j][0] = 0.f; acc[j][1] = 0.f; acc[j][2] = 0.f; acc[j][3] = 0.f;
    }

    for (int k = 0; k < K; k += 4) {
        float4 Bq[4];
        #pragma unroll
        for (int kk = 0; kk < 4; ++kk)
            Bq[kk] = *(const float4*)&Bs[(k + kk) * NPAD + cg * 4];
        #pragma unroll
        for (int j = 0; j < RPT; ++j) {
            const float4 Aq = *(const float4*)&As[(rg + RG * j) * K + k];
            #pragma unroll
            for (int c = 0; c < 4; ++c) {
                const float b0 = ((const float*)&Bq[0])[c];
                const float b1 = ((const float*)&Bq[1])[c];
                const float b2 = ((const float*)&Bq[2])[c];
                const float b3 = ((const float*)&Bq[3])[c];
                float a = acc[j][c];
                a = fmaf(Aq.x, b0, a);
                a = fmaf(Aq.y, b1, a);
                a = fmaf(Aq.z, b2, a);
                a = fmaf(Aq.w, b3, a);
                acc[j][c] = a;
            }
        }
    }

    // bias for this thread's 4 cols (guarded for N=121 tail)
    float bv[4];
    #pragma unroll
    for (int c = 0; c < 4; ++c) {
        int col = cg * 4 + c;
        bv[c] = (bias && col < N) ? bias[col] : 0.f;
    }

    #pragma unroll
    for (int j = 0; j < RPT; ++j) {
        const int r = row_base + rg + RG * j;
        if (r >= M) continue;
        const float sc = rowscale ? rowscale[r] : 1.0f;
        float o[4];
        #pragma unroll
        for (int c = 0; c < 4; ++c) o[c] = fmaf(acc[j][c], sc, bv[c]);
        OT* Crow = C + (size_t)r * N;
        if constexpr (sizeof(OT) == 4 && (N % 4 == 0)) {
            *(float4*)&Crow[cg * 4] = make_float4(o[0], o[1], o[2], o[3]);
        } else if constexpr (sizeof(OT) == 2 && (N % 4 == 0)) {
            __half2* p = (__half2*)&Crow[cg * 4];
            p[0] = __floats2half2_rn(o[0], o[1]);
            p[1] = __floats2half2_rn(o[2], o[3]);
        } else {
            #pragma unroll
            for (int c = 0; c < 4; ++c) {
                int col = cg * 4 + c;
                if (col < N) Crow[col] = (OT)o[c];
            }
        }
    }
}

// ---- pull aggregation: one wave per dst node, lanes = 64 features ----
// out[r] = relu(dinv[r] * (feat2[r] + sum_{s in N_in(r)} feat2[s]) + bias)
// feat2 is fp16 (128 B/row gather), already scaled by dinv[src]; fp32 accum.
__global__ __launch_bounds__(256) void aggregate(
        const __half* __restrict__ feat2, const int* __restrict__ rp,
        const int* __restrict__ srcs, const float* __restrict__ dinv,
        const float* __restrict__ bias, float* __restrict__ out, int N) {
    size_t gid = (size_t)blockIdx.x * blockDim.x + threadIdx.x;
    int r = (int)(gid >> 6);
    int f = (int)(gid & 63);
    if (r >= N) return;
    int beg = rp[r], end = rp[r + 1];
    float acc = __half2float(feat2[((size_t)r << 6) + f]);  // self-loop term
    int e = beg;
    for (; e + 8 <= end; e += 8) {  // 8 independent gathers in flight
        int s0 = srcs[e], s1 = srcs[e + 1], s2 = srcs[e + 2], s3 = srcs[e + 3];
        int s4 = srcs[e + 4], s5 = srcs[e + 5], s6 = srcs[e + 6], s7 = srcs[e + 7];
        float v0 = __half2float(feat2[((size_t)s0 << 6) + f]);
        float v1 = __half2float(feat2[((size_t)s1 << 6) + f]);
        float v2 = __half2float(feat2[((size_t)s2 << 6) + f]);
        float v3 = __half2float(feat2[((size_t)s3 << 6) + f]);
        float v4 = __half2float(feat2[((size_t)s4 << 6) + f]);
        float v5 = __half2float(feat2[((size_t)s5 << 6) + f]);
        float v6 = __half2float(feat2[((size_t)s6 << 6) + f]);
        float v7 = __half2float(feat2[((size_t)s7 << 6) + f]);
        acc += v0; acc += v1; acc += v2; acc += v3;
        acc += v4; acc += v5; acc += v6; acc += v7;
    }
    for (; e < end; ++e) acc += __half2float(feat2[((size_t)srcs[e] << 6) + f]);
    out[gid] = fmaxf(fmaf(acc, dinv[r], bias[f]), 0.f);
}

extern "C" void kernel_launch(void* const* d_in, const int* in_sizes, int n_in,
                              void* d_out, int out_size, void* d_ws, size_t ws_size,
                              hipStream_t stream) {
    const float* x    = (const float*)d_in[0];
    const int*   ei   = (const int*)d_in[1];
    const float* W1   = (const float*)d_in[2];
    const float* b1   = (const float*)d_in[3];
    const float* W2   = (const float*)d_in[4];
    const float* b2   = (const float*)d_in[5];
    const float* Wout = (const float*)d_in[6];
    const float* bout = (const float*)d_in[7];
    float* out = (float*)d_out;

    const int N = in_sizes[0] / IN_DIM;   // 100000
    const int E = in_sizes[1] / 2;        // 3200000
    const int* srcI = ei;
    const int* dstI = ei + E;

    const int nbuk = (N + 255) >> 8;      // 391 coarse buckets
    const int M1 = nbuk * NB_BLK;         // 100096 count entries
    const int chunk = (E + NB_BLK - 1) / NB_BLK;

    // workspace carve-up
    int*    row_ptr = (int*)d_ws;                   // [N+1]
    float*  dinv    = (float*)(row_ptr + (N + 1));  // [N]
    int*    counts  = (int*)(dinv + N);             // [M1]
    int*    base    = counts + M1;                  // [M1]
    int*    bsums2  = base + M1;                    // [512]
    int*    srcs    = bsums2 + 512;                 // [E]
    __half* feat2   = (__half*)(srcs + E);          // [N, HID] fp16 (12.8 MB)
    float*  hbuf    = (float*)(feat2 + (size_t)N * HID);  // [N, HID] fp32
    int*    bucketed = (int*)feat2;                 // [E] ints, aliases feat2 (dead until GEMM1)

    const int nbM = (M1 + 255) / 256;               // 391
    const int gemmBlocks = (N + 63) / 64;
    const int aggBlocks = (int)(((size_t)N * HID + 255) / 256);
    const size_t ldsBuk = (size_t)nbuk * sizeof(int);

    // ---- two-level sort: edges grouped by dst into srcs; emits row_ptr+dinv ----
    bucket_count<<<NB_BLK, 256, ldsBuk, stream>>>(dstI, counts, nbuk, chunk, E);
    scan1<<<nbM, 256, 0, stream>>>(counts, base, bsums2, M1);
    scan2<<<1, 512, 0, stream>>>(bsums2, nbM);
    scan_add<<<nbM, 256, 0, stream>>>(base, bsums2, M1);
    bucket_scatter<<<NB_BLK, 256, ldsBuk, stream>>>(srcI, dstI, base, bucketed, nbuk, chunk, E);
    bucket_sort<<<nbuk, 256, 0, stream>>>(bucketed, base, srcs, row_ptr, dinv, nbuk, N, E);

    // ---- layer 1 ----
    gemm_kernel<IN_DIM, HID, __half><<<gemmBlocks, 256, 0, stream>>>(x, W1, nullptr, dinv, feat2, N);
    aggregate<<<aggBlocks, 256, 0, stream>>>(feat2, row_ptr, srcs, dinv, b1, hbuf, N);

    // ---- layer 2 ----
    gemm_kernel<HID, HID, __half><<<gemmBlocks, 256, 0, stream>>>(hbuf, W2, nullptr, dinv, feat2, N);
    aggregate<<<aggBlocks, 256, 0, stream>>>(feat2, row_ptr, srcs, dinv, b2, hbuf, N);

    // ---- head ----
    gemm_kernel<HID, N_LAB, float><<<gemmBlocks, 256, 0, stream>>>(hbuf, Wout, bout, nullptr, out, N);
}